// Round 2
// baseline (1758.935 us; speedup 1.0000x reference)
//
#include <hip/hip_runtime.h>
#include <math.h>

#define NQ 12
#define DEPTH 3
#define FEAT 768
#define NCLS 10
#define PI_HALF 1.57079632679489662f

// ---------- lane-swap helpers: value of (this expression) from lane ^ M ----------
#define DPPF(v, ctrl) __int_as_float(__builtin_amdgcn_update_dpp(0, __float_as_int(v), (ctrl), 0xF, 0xF, true))

template<int M>
__device__ __forceinline__ float swx(float v) {
    if constexpr (M == 1) {          // quad_perm [1,0,3,2]
        return DPPF(v, 0xB1);
    } else if constexpr (M == 2) {   // quad_perm [2,3,0,1]
        return DPPF(v, 0x4E);
    } else if constexpr (M == 4) {   // row_half_mirror (xor7) then quad_perm [3,2,1,0] (xor3)
        float t = DPPF(v, 0x141);
        return DPPF(t, 0x1B);
    } else if constexpr (M == 8) {   // row_ror:8 within 16 lanes == xor8
        return DPPF(v, 0x128);
    } else if constexpr (M == 16) {  // ds_swizzle bitmode: xor=16, and=0x1F
        return __int_as_float(__builtin_amdgcn_ds_swizzle(__float_as_int(v), 0x401F));
    } else {                         // M == 32
        return __shfl_xor(v, 32, 64);
    }
}

__device__ __forceinline__ float allred(float v) {
    v += swx<1>(v); v += swx<2>(v); v += swx<4>(v);
    v += swx<8>(v); v += swx<16>(v); v += swx<32>(v);
    return v;   // sum over all 64 lanes, in every lane
}

// ---------- gates ----------
// State: amp index i = (lane<<6) | j.  Wire w in [0,5]  -> lane mask 32>>w.
//                                      Wire w in [6,11] -> reg  mask 32>>(w-6).

template<int JM>
__device__ __forceinline__ void ry_reg(float (&vr)[64], float (&vi)[64], float c, float s) {
    #pragma unroll
    for (int j = 0; j < 64; ++j) if (!(j & JM)) {
        const int j1 = j | JM;
        float r0 = vr[j], i0 = vi[j], r1 = vr[j1], i1 = vi[j1];
        vr[j]  = c * r0 - s * r1;  vi[j]  = c * i0 - s * i1;
        vr[j1] = s * r0 + c * r1;  vi[j1] = s * i0 + c * i1;
    }
}

template<int LM>
__device__ __forceinline__ void ry_lane(float (&vr)[64], float (&vi)[64], float c, float s, int lane) {
    const float cp = (lane & LM) ? s : -s;   // bit0: c*v - s*p ; bit1: c*v + s*p
    #pragma unroll
    for (int j = 0; j < 64; ++j) {
        float pr = swx<LM>(vr[j]), pi = swx<LM>(vi[j]);
        vr[j] = c * vr[j] + cp * pr;
        vi[j] = c * vi[j] + cp * pi;
    }
}

template<int JM>
__device__ __forceinline__ void rot_reg(float (&vr)[64], float (&vi)[64], const float* m) {
    const float m00r = m[0], m00i = m[1], m01r = m[2], m01i = m[3];
    const float m10r = m[4], m10i = m[5], m11r = m[6], m11i = m[7];
    #pragma unroll
    for (int j = 0; j < 64; ++j) if (!(j & JM)) {
        const int j1 = j | JM;
        float r0 = vr[j], i0 = vi[j], r1 = vr[j1], i1 = vi[j1];
        vr[j]  = m00r * r0 - m00i * i0 + m01r * r1 - m01i * i1;
        vi[j]  = m00r * i0 + m00i * r0 + m01r * i1 + m01i * r1;
        vr[j1] = m10r * r0 - m10i * i0 + m11r * r1 - m11i * i1;
        vi[j1] = m10r * i0 + m10i * r0 + m11r * i1 + m11i * r1;
    }
}

template<int LM>
__device__ __forceinline__ void rot_lane(float (&vr)[64], float (&vi)[64], const float* m, int lane) {
    const bool b = (lane & LM) != 0;
    const float csr = b ? m[6] : m[0], csi = b ? m[7] : m[1];   // coeff * self
    const float cpr = b ? m[4] : m[2], cpi = b ? m[5] : m[3];   // coeff * partner
    #pragma unroll
    for (int j = 0; j < 64; ++j) {
        float pr = swx<LM>(vr[j]), pi = swx<LM>(vi[j]);
        float r = vr[j], i = vi[j];
        vr[j] = csr * r - csi * i + cpr * pr - cpi * pi;
        vi[j] = csr * i + csi * r + cpr * pi + cpi * pr;
    }
}

template<int JC, int JT>
__device__ __forceinline__ void cnot_rr(float (&vr)[64], float (&vi)[64]) {
    #pragma unroll
    for (int j = 0; j < 64; ++j) if ((j & JC) && !(j & JT)) {
        const int j1 = j | JT;
        float tr = vr[j]; vr[j] = vr[j1]; vr[j1] = tr;
        float ti = vi[j]; vi[j] = vi[j1]; vi[j1] = ti;
    }
}

template<int JC, int LT>
__device__ __forceinline__ void cnot_rl(float (&vr)[64], float (&vi)[64]) {
    #pragma unroll
    for (int j = 0; j < 64; ++j) if (j & JC) {
        vr[j] = swx<LT>(vr[j]);
        vi[j] = swx<LT>(vi[j]);
    }
}

template<int LC, int JT>
__device__ __forceinline__ void cnot_lr(float (&vr)[64], float (&vi)[64], int lane) {
    const bool b = (lane & LC) != 0;
    #pragma unroll
    for (int j = 0; j < 64; ++j) if (!(j & JT)) {
        const int j1 = j | JT;
        float r0 = vr[j], r1 = vr[j1];
        vr[j] = b ? r1 : r0;  vr[j1] = b ? r0 : r1;
        float i0 = vi[j], i1 = vi[j1];
        vi[j] = b ? i1 : i0;  vi[j1] = b ? i0 : i1;
    }
}

template<int LC, int LT>
__device__ __forceinline__ void cnot_ll(float (&vr)[64], float (&vi)[64], int lane) {
    const bool b = (lane & LC) != 0;
    #pragma unroll
    for (int j = 0; j < 64; ++j) {
        float pr = swx<LT>(vr[j]);
        float pi = swx<LT>(vi[j]);
        vr[j] = b ? pr : vr[j];
        vi[j] = b ? pi : vi[j];
    }
}

__global__ __launch_bounds__(256, 2) void qcircuit_reg(
    const float* __restrict__ x,    // [B, 768]
    const float* __restrict__ Wp,   // [12, 768]
    const float* __restrict__ w,    // [3, 12, 3]
    const float* __restrict__ Wo,   // [10, 12]
    const float* __restrict__ bo,   // [10]
    float* __restrict__ out)        // [B, 10]
{
    const int t = threadIdx.x;
    const int wave = t >> 6;
    const int lane = t & 63;
    const int b = blockIdx.x * 4 + wave;

    __shared__ float rotm[DEPTH * NQ][8];   // batch-independent Rot matrices
    if (t < DEPTH * NQ) {
        float phi = w[t * 3 + 0], th = w[t * 3 + 1], om = w[t * 3 + 2];
        float ct = cosf(0.5f * th), sn = sinf(0.5f * th);
        float a0 = -0.5f * (phi + om);
        float a1 = 0.5f * (phi - om);
        float c0 = cosf(a0), s0 = sinf(a0);
        float c1 = cosf(a1), s1 = sinf(a1);
        rotm[t][0] = c0 * ct;  rotm[t][1] = s0 * ct;    // m00
        rotm[t][2] = -c1 * sn; rotm[t][3] = -s1 * sn;   // m01
        rotm[t][4] = c1 * sn;  rotm[t][5] = -s1 * sn;   // m10
        rotm[t][6] = c0 * ct;  rotm[t][7] = -s0 * ct;   // m11
    }
    __syncthreads();

    // ---------------- projection: acc[q] = x[b,:] . Wp[q,:] ----------------
    float acc[NQ];
    #pragma unroll
    for (int q = 0; q < NQ; ++q) acc[q] = 0.f;
    const float4* x4  = reinterpret_cast<const float4*>(x + (size_t)b * FEAT);
    const float4* Wp4 = reinterpret_cast<const float4*>(Wp);
    #pragma unroll
    for (int k = 0; k < 3; ++k) {
        float4 xv = x4[lane + 64 * k];
        #pragma unroll
        for (int q = 0; q < NQ; ++q) {
            float4 wv = Wp4[q * 192 + lane + 64 * k];
            acc[q] += xv.x * wv.x + xv.y * wv.y + xv.z * wv.z + xv.w * wv.w;
        }
    }
    float ac[NQ], as_[NQ];
    #pragma unroll
    for (int q = 0; q < NQ; ++q) {
        float s = allred(acc[q]);
        float h = 0.5f * (tanhf(s) * PI_HALF);
        ac[q] = cosf(h);
        as_[q] = sinf(h);
    }

    // ---------------- init |0...0> ----------------
    float vr[64], vi[64];
    #pragma unroll
    for (int j = 0; j < 64; ++j) { vr[j] = 0.f; vi[j] = 0.f; }
    vr[0] = (lane == 0) ? 1.f : 0.f;

    // ---------------- RY encoding ----------------
    ry_lane<32>(vr, vi, ac[0], as_[0], lane);
    ry_lane<16>(vr, vi, ac[1], as_[1], lane);
    ry_lane< 8>(vr, vi, ac[2], as_[2], lane);
    ry_lane< 4>(vr, vi, ac[3], as_[3], lane);
    ry_lane< 2>(vr, vi, ac[4], as_[4], lane);
    ry_lane< 1>(vr, vi, ac[5], as_[5], lane);
    ry_reg <32>(vr, vi, ac[6], as_[6]);
    ry_reg <16>(vr, vi, ac[7], as_[7]);
    ry_reg < 8>(vr, vi, ac[8], as_[8]);
    ry_reg < 4>(vr, vi, ac[9], as_[9]);
    ry_reg < 2>(vr, vi, ac[10], as_[10]);
    ry_reg < 1>(vr, vi, ac[11], as_[11]);

    // ---------------- StronglyEntanglingLayers ----------------
    #pragma unroll 1
    for (int l = 0; l < DEPTH; ++l) {
        const float* mb = rotm[l * NQ];
        rot_lane<32>(vr, vi, mb + 0 * 8, lane);
        rot_lane<16>(vr, vi, mb + 1 * 8, lane);
        rot_lane< 8>(vr, vi, mb + 2 * 8, lane);
        rot_lane< 4>(vr, vi, mb + 3 * 8, lane);
        rot_lane< 2>(vr, vi, mb + 4 * 8, lane);
        rot_lane< 1>(vr, vi, mb + 5 * 8, lane);
        rot_reg <32>(vr, vi, mb + 6 * 8);
        rot_reg <16>(vr, vi, mb + 7 * 8);
        rot_reg < 8>(vr, vi, mb + 8 * 8);
        rot_reg < 4>(vr, vi, mb + 9 * 8);
        rot_reg < 2>(vr, vi, mb + 10 * 8);
        rot_reg < 1>(vr, vi, mb + 11 * 8);
        if (l == 0) {          // r = 1
            cnot_ll<32, 16>(vr, vi, lane);   // (0,1)
            cnot_ll<16,  8>(vr, vi, lane);   // (1,2)
            cnot_ll< 8,  4>(vr, vi, lane);   // (2,3)
            cnot_ll< 4,  2>(vr, vi, lane);   // (3,4)
            cnot_ll< 2,  1>(vr, vi, lane);   // (4,5)
            cnot_lr< 1, 32>(vr, vi, lane);   // (5,6)
            cnot_rr<32, 16>(vr, vi);         // (6,7)
            cnot_rr<16,  8>(vr, vi);         // (7,8)
            cnot_rr< 8,  4>(vr, vi);         // (8,9)
            cnot_rr< 4,  2>(vr, vi);         // (9,10)
            cnot_rr< 2,  1>(vr, vi);         // (10,11)
            cnot_rl< 1, 32>(vr, vi);         // (11,0)
        } else if (l == 1) {   // r = 2
            cnot_ll<32,  8>(vr, vi, lane);   // (0,2)
            cnot_ll<16,  4>(vr, vi, lane);   // (1,3)
            cnot_ll< 8,  2>(vr, vi, lane);   // (2,4)
            cnot_ll< 4,  1>(vr, vi, lane);   // (3,5)
            cnot_lr< 2, 32>(vr, vi, lane);   // (4,6)
            cnot_lr< 1, 16>(vr, vi, lane);   // (5,7)
            cnot_rr<32,  8>(vr, vi);         // (6,8)
            cnot_rr<16,  4>(vr, vi);         // (7,9)
            cnot_rr< 8,  2>(vr, vi);         // (8,10)
            cnot_rr< 4,  1>(vr, vi);         // (9,11)
            cnot_rl< 2, 32>(vr, vi);         // (10,0)
            cnot_rl< 1, 16>(vr, vi);         // (11,1)
        } else {               // r = 3
            cnot_ll<32,  4>(vr, vi, lane);   // (0,3)
            cnot_ll<16,  2>(vr, vi, lane);   // (1,4)
            cnot_ll< 8,  1>(vr, vi, lane);   // (2,5)
            cnot_lr< 4, 32>(vr, vi, lane);   // (3,6)
            cnot_lr< 2, 16>(vr, vi, lane);   // (4,7)
            cnot_lr< 1,  8>(vr, vi, lane);   // (5,8)
            cnot_rr<32,  4>(vr, vi);         // (6,9)
            cnot_rr<16,  2>(vr, vi);         // (7,10)
            cnot_rr< 8,  1>(vr, vi);         // (8,11)
            cnot_rl< 4, 32>(vr, vi);         // (9,0)
            cnot_rl< 2, 16>(vr, vi);         // (10,1)
            cnot_rl< 1,  8>(vr, vi);         // (11,2)
        }
    }

    // ---------------- PauliZ expectations ----------------
    float ptot = 0.f, zn32 = 0.f, zn16 = 0.f, zn8 = 0.f, zn4 = 0.f, zn2 = 0.f, zn1 = 0.f;
    #pragma unroll
    for (int j = 0; j < 64; ++j) {
        float p = vr[j] * vr[j] + vi[j] * vi[j];
        ptot += p;
        if (j & 32) zn32 += p;
        if (j & 16) zn16 += p;
        if (j & 8)  zn8  += p;
        if (j & 4)  zn4  += p;
        if (j & 2)  zn2  += p;
        if (j & 1)  zn1  += p;
    }
    float z[NQ];
    z[0] = allred((lane & 32) ? -ptot : ptot);
    z[1] = allred((lane & 16) ? -ptot : ptot);
    z[2] = allred((lane &  8) ? -ptot : ptot);
    z[3] = allred((lane &  4) ? -ptot : ptot);
    z[4] = allred((lane &  2) ? -ptot : ptot);
    z[5] = allred((lane &  1) ? -ptot : ptot);
    z[6]  = allred(ptot - 2.f * zn32);
    z[7]  = allred(ptot - 2.f * zn16);
    z[8]  = allred(ptot - 2.f * zn8);
    z[9]  = allred(ptot - 2.f * zn4);
    z[10] = allred(ptot - 2.f * zn2);
    z[11] = allred(ptot - 2.f * zn1);

    // ---------------- output head ----------------
    if (lane < NCLS) {
        float o = bo[lane];
        #pragma unroll
        for (int q = 0; q < NQ; ++q) o = fmaf(z[q], Wo[lane * NQ + q], o);
        out[(size_t)b * NCLS + lane] = o;
    }
}

extern "C" void kernel_launch(void* const* d_in, const int* in_sizes, int n_in,
                              void* d_out, int out_size, void* d_ws, size_t ws_size,
                              hipStream_t stream) {
    const float* x  = (const float*)d_in[0];   // [B,768]
    const float* Wp = (const float*)d_in[1];   // [12,768]
    const float* w  = (const float*)d_in[2];   // [3,12,3]
    const float* Wo = (const float*)d_in[3];   // [10,12]
    const float* bo = (const float*)d_in[4];   // [10]
    float* out = (float*)d_out;

    const int B = in_sizes[0] / FEAT;          // 4096
    qcircuit_reg<<<B / 4, 256, 0, stream>>>(x, Wp, w, Wo, bo, out);
}

// Round 3
// 412.023 us; speedup vs baseline: 4.2690x; 4.2690x over previous
//
#include <hip/hip_runtime.h>
#include <math.h>

#define NQ 12
#define DEPTH 3
#define FEAT 768
#define NCLS 10
#define PI_HALF 1.57079632679489662f

// ---------- lane-swap helpers: value of (this expression) from lane ^ M ----------
#define DPPF(v, ctrl) __int_as_float(__builtin_amdgcn_update_dpp(0, __float_as_int(v), (ctrl), 0xF, 0xF, true))

template<int M>
__device__ __forceinline__ float swx(float v) {
    if constexpr (M == 1) {          // quad_perm [1,0,3,2]
        return DPPF(v, 0xB1);
    } else if constexpr (M == 2) {   // quad_perm [2,3,0,1]
        return DPPF(v, 0x4E);
    } else if constexpr (M == 4) {   // ds_swizzle bitmode xor=4 (DS pipe, overlaps VALU)
        return __int_as_float(__builtin_amdgcn_ds_swizzle(__float_as_int(v), 0x101F));
    } else if constexpr (M == 8) {   // row_ror:8 within 16 lanes == xor8
        return DPPF(v, 0x128);
    } else if constexpr (M == 16) {  // ds_swizzle bitmode: xor=16
        return __int_as_float(__builtin_amdgcn_ds_swizzle(__float_as_int(v), 0x401F));
    } else {                         // M == 32
        return __shfl_xor(v, 32, 64);
    }
}

__device__ __forceinline__ float allred(float v) {
    v += swx<1>(v); v += swx<2>(v); v += swx<4>(v);
    v += swx<8>(v); v += swx<16>(v); v += swx<32>(v);
    return v;   // sum over all 64 lanes, in every lane
}

// ---------- gates ----------
// State: amp index i = (lane<<6) | j.  Wire w in [0,5]  -> lane mask 32>>w.
//                                      Wire w in [6,11] -> reg  mask 32>>(w-6).

template<int JM>
__device__ __forceinline__ void ry_reg(float (&vr)[64], float (&vi)[64], float c, float s) {
    #pragma unroll
    for (int j = 0; j < 64; ++j) if (!(j & JM)) {
        const int j1 = j | JM;
        float r0 = vr[j], i0 = vi[j], r1 = vr[j1], i1 = vi[j1];
        vr[j]  = c * r0 - s * r1;  vi[j]  = c * i0 - s * i1;
        vr[j1] = s * r0 + c * r1;  vi[j1] = s * i0 + c * i1;
    }
}

template<int LM>
__device__ __forceinline__ void ry_lane(float (&vr)[64], float (&vi)[64], float c, float s, int lane) {
    const float cp = (lane & LM) ? s : -s;   // bit0: c*v - s*p ; bit1: c*v + s*p
    #pragma unroll
    for (int j = 0; j < 64; ++j) {
        float pr = swx<LM>(vr[j]), pi = swx<LM>(vi[j]);
        vr[j] = c * vr[j] + cp * pr;
        vi[j] = c * vi[j] + cp * pi;
    }
}

template<int JM>
__device__ __forceinline__ void rot_reg(float (&vr)[64], float (&vi)[64], const float* m) {
    const float m00r = m[0], m00i = m[1], m01r = m[2], m01i = m[3];
    const float m10r = m[4], m10i = m[5], m11r = m[6], m11i = m[7];
    #pragma unroll
    for (int j = 0; j < 64; ++j) if (!(j & JM)) {
        const int j1 = j | JM;
        float r0 = vr[j], i0 = vi[j], r1 = vr[j1], i1 = vi[j1];
        vr[j]  = m00r * r0 - m00i * i0 + m01r * r1 - m01i * i1;
        vi[j]  = m00r * i0 + m00i * r0 + m01r * i1 + m01i * r1;
        vr[j1] = m10r * r0 - m10i * i0 + m11r * r1 - m11i * i1;
        vi[j1] = m10r * i0 + m10i * r0 + m11r * i1 + m11i * r1;
    }
}

template<int LM>
__device__ __forceinline__ void rot_lane(float (&vr)[64], float (&vi)[64], const float* m, int lane) {
    const bool b = (lane & LM) != 0;
    const float csr = b ? m[6] : m[0], csi = b ? m[7] : m[1];   // coeff * self
    const float cpr = b ? m[4] : m[2], cpi = b ? m[5] : m[3];   // coeff * partner
    #pragma unroll
    for (int j = 0; j < 64; ++j) {
        float pr = swx<LM>(vr[j]), pi = swx<LM>(vi[j]);
        float r = vr[j], i = vi[j];
        vr[j] = csr * r - csi * i + cpr * pr - cpi * pi;
        vi[j] = csr * i + csi * r + cpr * pi + cpi * pr;
    }
}

template<int JC, int JT>
__device__ __forceinline__ void cnot_rr(float (&vr)[64], float (&vi)[64]) {
    #pragma unroll
    for (int j = 0; j < 64; ++j) if ((j & JC) && !(j & JT)) {
        const int j1 = j | JT;
        float tr = vr[j]; vr[j] = vr[j1]; vr[j1] = tr;
        float ti = vi[j]; vi[j] = vi[j1]; vi[j1] = ti;
    }
}

template<int JC, int LT>
__device__ __forceinline__ void cnot_rl(float (&vr)[64], float (&vi)[64]) {
    #pragma unroll
    for (int j = 0; j < 64; ++j) if (j & JC) {
        vr[j] = swx<LT>(vr[j]);
        vi[j] = swx<LT>(vi[j]);
    }
}

template<int LC, int JT>
__device__ __forceinline__ void cnot_lr(float (&vr)[64], float (&vi)[64], int lane) {
    const bool b = (lane & LC) != 0;
    #pragma unroll
    for (int j = 0; j < 64; ++j) if (!(j & JT)) {
        const int j1 = j | JT;
        float r0 = vr[j], r1 = vr[j1];
        vr[j] = b ? r1 : r0;  vr[j1] = b ? r0 : r1;
        float i0 = vi[j], i1 = vi[j1];
        vi[j] = b ? i1 : i0;  vi[j1] = b ? i0 : i1;
    }
}

template<int LC, int LT>
__device__ __forceinline__ void cnot_ll(float (&vr)[64], float (&vi)[64], int lane) {
    const bool b = (lane & LC) != 0;
    #pragma unroll
    for (int j = 0; j < 64; ++j) {
        float pr = swx<LT>(vr[j]);
        float pi = swx<LT>(vi[j]);
        vr[j] = b ? pr : vr[j];
        vi[j] = b ? pi : vi[j];
    }
}

// One wave per block: full 512-VGPR budget (min 1 wave/EU), no spill of the
// 128-reg statevector.
__global__ __launch_bounds__(64, 1) void qcircuit_reg(
    const float* __restrict__ x,    // [B, 768]
    const float* __restrict__ Wp,   // [12, 768]
    const float* __restrict__ w,    // [3, 12, 3]
    const float* __restrict__ Wo,   // [10, 12]
    const float* __restrict__ bo,   // [10]
    float* __restrict__ out)        // [B, 10]
{
    const int lane = threadIdx.x;
    const int b = blockIdx.x;

    __shared__ float rotm[DEPTH * NQ][8];   // batch-independent Rot matrices
    if (lane < DEPTH * NQ) {
        float phi = w[lane * 3 + 0], th = w[lane * 3 + 1], om = w[lane * 3 + 2];
        float ct = cosf(0.5f * th), sn = sinf(0.5f * th);
        float a0 = -0.5f * (phi + om);
        float a1 = 0.5f * (phi - om);
        float c0 = cosf(a0), s0 = sinf(a0);
        float c1 = cosf(a1), s1 = sinf(a1);
        rotm[lane][0] = c0 * ct;  rotm[lane][1] = s0 * ct;    // m00
        rotm[lane][2] = -c1 * sn; rotm[lane][3] = -s1 * sn;   // m01
        rotm[lane][4] = c1 * sn;  rotm[lane][5] = -s1 * sn;   // m10
        rotm[lane][6] = c0 * ct;  rotm[lane][7] = -s0 * ct;   // m11
    }
    __syncthreads();

    // ---------------- projection: acc[q] = x[b,:] . Wp[q,:] ----------------
    float acc[NQ];
    #pragma unroll
    for (int q = 0; q < NQ; ++q) acc[q] = 0.f;
    const float4* x4  = reinterpret_cast<const float4*>(x + (size_t)b * FEAT);
    const float4* Wp4 = reinterpret_cast<const float4*>(Wp);
    #pragma unroll
    for (int k = 0; k < 3; ++k) {
        float4 xv = x4[lane + 64 * k];
        #pragma unroll
        for (int q = 0; q < NQ; ++q) {
            float4 wv = Wp4[q * 192 + lane + 64 * k];
            acc[q] += xv.x * wv.x + xv.y * wv.y + xv.z * wv.z + xv.w * wv.w;
        }
    }
    float ac[NQ], as_[NQ];
    #pragma unroll
    for (int q = 0; q < NQ; ++q) {
        float s = allred(acc[q]);
        float h = 0.5f * (tanhf(s) * PI_HALF);
        ac[q] = cosf(h);
        as_[q] = sinf(h);
    }

    // ---------------- init |0...0> ----------------
    float vr[64], vi[64];
    #pragma unroll
    for (int j = 0; j < 64; ++j) { vr[j] = 0.f; vi[j] = 0.f; }
    vr[0] = (lane == 0) ? 1.f : 0.f;

    // ---------------- RY encoding ----------------
    ry_lane<32>(vr, vi, ac[0], as_[0], lane);
    ry_lane<16>(vr, vi, ac[1], as_[1], lane);
    ry_lane< 8>(vr, vi, ac[2], as_[2], lane);
    ry_lane< 4>(vr, vi, ac[3], as_[3], lane);
    ry_lane< 2>(vr, vi, ac[4], as_[4], lane);
    ry_lane< 1>(vr, vi, ac[5], as_[5], lane);
    ry_reg <32>(vr, vi, ac[6], as_[6]);
    ry_reg <16>(vr, vi, ac[7], as_[7]);
    ry_reg < 8>(vr, vi, ac[8], as_[8]);
    ry_reg < 4>(vr, vi, ac[9], as_[9]);
    ry_reg < 2>(vr, vi, ac[10], as_[10]);
    ry_reg < 1>(vr, vi, ac[11], as_[11]);

    // ---------------- StronglyEntanglingLayers ----------------
    #pragma unroll 1
    for (int l = 0; l < DEPTH; ++l) {
        const float* mb = rotm[l * NQ];
        rot_lane<32>(vr, vi, mb + 0 * 8, lane);
        rot_lane<16>(vr, vi, mb + 1 * 8, lane);
        rot_lane< 8>(vr, vi, mb + 2 * 8, lane);
        rot_lane< 4>(vr, vi, mb + 3 * 8, lane);
        rot_lane< 2>(vr, vi, mb + 4 * 8, lane);
        rot_lane< 1>(vr, vi, mb + 5 * 8, lane);
        rot_reg <32>(vr, vi, mb + 6 * 8);
        rot_reg <16>(vr, vi, mb + 7 * 8);
        rot_reg < 8>(vr, vi, mb + 8 * 8);
        rot_reg < 4>(vr, vi, mb + 9 * 8);
        rot_reg < 2>(vr, vi, mb + 10 * 8);
        rot_reg < 1>(vr, vi, mb + 11 * 8);
        if (l == 0) {          // r = 1
            cnot_ll<32, 16>(vr, vi, lane);   // (0,1)
            cnot_ll<16,  8>(vr, vi, lane);   // (1,2)
            cnot_ll< 8,  4>(vr, vi, lane);   // (2,3)
            cnot_ll< 4,  2>(vr, vi, lane);   // (3,4)
            cnot_ll< 2,  1>(vr, vi, lane);   // (4,5)
            cnot_lr< 1, 32>(vr, vi, lane);   // (5,6)
            cnot_rr<32, 16>(vr, vi);         // (6,7)
            cnot_rr<16,  8>(vr, vi);         // (7,8)
            cnot_rr< 8,  4>(vr, vi);         // (8,9)
            cnot_rr< 4,  2>(vr, vi);         // (9,10)
            cnot_rr< 2,  1>(vr, vi);         // (10,11)
            cnot_rl< 1, 32>(vr, vi);         // (11,0)
        } else if (l == 1) {   // r = 2
            cnot_ll<32,  8>(vr, vi, lane);   // (0,2)
            cnot_ll<16,  4>(vr, vi, lane);   // (1,3)
            cnot_ll< 8,  2>(vr, vi, lane);   // (2,4)
            cnot_ll< 4,  1>(vr, vi, lane);   // (3,5)
            cnot_lr< 2, 32>(vr, vi, lane);   // (4,6)
            cnot_lr< 1, 16>(vr, vi, lane);   // (5,7)
            cnot_rr<32,  8>(vr, vi);         // (6,8)
            cnot_rr<16,  4>(vr, vi);         // (7,9)
            cnot_rr< 8,  2>(vr, vi);         // (8,10)
            cnot_rr< 4,  1>(vr, vi);         // (9,11)
            cnot_rl< 2, 32>(vr, vi);         // (10,0)
            cnot_rl< 1, 16>(vr, vi);         // (11,1)
        } else {               // r = 3
            cnot_ll<32,  4>(vr, vi, lane);   // (0,3)
            cnot_ll<16,  2>(vr, vi, lane);   // (1,4)
            cnot_ll< 8,  1>(vr, vi, lane);   // (2,5)
            cnot_lr< 4, 32>(vr, vi, lane);   // (3,6)
            cnot_lr< 2, 16>(vr, vi, lane);   // (4,7)
            cnot_lr< 1,  8>(vr, vi, lane);   // (5,8)
            cnot_rr<32,  4>(vr, vi);         // (6,9)
            cnot_rr<16,  2>(vr, vi);         // (7,10)
            cnot_rr< 8,  1>(vr, vi);         // (8,11)
            cnot_rl< 4, 32>(vr, vi);         // (9,0)
            cnot_rl< 2, 16>(vr, vi);         // (10,1)
            cnot_rl< 1,  8>(vr, vi);         // (11,2)
        }
    }

    // ---------------- PauliZ expectations ----------------
    float ptot = 0.f, zn32 = 0.f, zn16 = 0.f, zn8 = 0.f, zn4 = 0.f, zn2 = 0.f, zn1 = 0.f;
    #pragma unroll
    for (int j = 0; j < 64; ++j) {
        float p = vr[j] * vr[j] + vi[j] * vi[j];
        ptot += p;
        if (j & 32) zn32 += p;
        if (j & 16) zn16 += p;
        if (j & 8)  zn8  += p;
        if (j & 4)  zn4  += p;
        if (j & 2)  zn2  += p;
        if (j & 1)  zn1  += p;
    }
    float z[NQ];
    z[0] = allred((lane & 32) ? -ptot : ptot);
    z[1] = allred((lane & 16) ? -ptot : ptot);
    z[2] = allred((lane &  8) ? -ptot : ptot);
    z[3] = allred((lane &  4) ? -ptot : ptot);
    z[4] = allred((lane &  2) ? -ptot : ptot);
    z[5] = allred((lane &  1) ? -ptot : ptot);
    z[6]  = allred(ptot - 2.f * zn32);
    z[7]  = allred(ptot - 2.f * zn16);
    z[8]  = allred(ptot - 2.f * zn8);
    z[9]  = allred(ptot - 2.f * zn4);
    z[10] = allred(ptot - 2.f * zn2);
    z[11] = allred(ptot - 2.f * zn1);

    // ---------------- output head ----------------
    if (lane < NCLS) {
        float o = bo[lane];
        #pragma unroll
        for (int q = 0; q < NQ; ++q) o = fmaf(z[q], Wo[lane * NQ + q], o);
        out[(size_t)b * NCLS + lane] = o;
    }
}

extern "C" void kernel_launch(void* const* d_in, const int* in_sizes, int n_in,
                              void* d_out, int out_size, void* d_ws, size_t ws_size,
                              hipStream_t stream) {
    const float* x  = (const float*)d_in[0];   // [B,768]
    const float* Wp = (const float*)d_in[1];   // [12,768]
    const float* w  = (const float*)d_in[2];   // [3,12,3]
    const float* Wo = (const float*)d_in[3];   // [10,12]
    const float* bo = (const float*)d_in[4];   // [10]
    float* out = (float*)d_out;

    const int B = in_sizes[0] / FEAT;          // 4096
    qcircuit_reg<<<B, 64, 0, stream>>>(x, Wp, w, Wo, bo, out);
}